// Round 4
// baseline (754.735 us; speedup 1.0000x reference)
//
#include <hip/hip_runtime.h>

// Reaction-diffusion: c += (D*lap(c) + rho*c*(1-c)) * dt/steps, clip [0,1], 20 steps.
// 192^3 fp32. One kernel per step, ping-pong via workspace.
//
// R4: flat float4 kernel, NO z-march. R2/R3's register z-pipeline created a
// load->use dependence across iterations (VGPR=32, ~2 loads in flight) and left
// the machine latency-bound (VALUBusy 9.7%). Here every thread does 9 fully
// independent loads (cm/cc/cp/ym/yp float4 + 2 scalar x-halo + D + rho), so the
// compiler batches them into one vmcnt group -> max memory-level parallelism.
// Grid 9216 blocks x 3 waves = 27648 waves (~32/CU, ramp-limited only).
// Block id = yc + 48*z: z-neighbor blocks differ by 48 = 0 mod 8 -> same XCD,
// so the large z-halo (full row-group) is served by the local L2.

constexpr int W = 192, H = 192, DZ = 192;
constexpr int PLANE = W * H;
constexpr int NELEM = W * H * DZ;
constexpr int XT = 48;           // x threads per block (float4 each: 48*4 = 192)
constexpr int YB = 4;            // y rows per block

__global__ __launch_bounds__(XT * YB) void rd_step(
    const float* __restrict__ c,
    const float* __restrict__ Dm,
    const float* __restrict__ rho,
    const float* __restrict__ dt,
    const int* __restrict__ steps,
    float* __restrict__ out)
{
    const int xt = threadIdx.x;              // 0..47
    const int yt = threadIdx.y;              // 0..3
    const int y  = blockIdx.x * YB + yt;     // 0..191
    const int z  = blockIdx.y;               // 0..191
    const int x4 = xt * 4;                   // 0,4,...,188
    const int zoff = z * PLANE + y * W + x4;

    const float4 zero = make_float4(0.f, 0.f, 0.f, 0.f);

    // 9 independent loads — issue all before any use.
    const float4 cc = *(const float4*)(c + zoff);
    const float4 cm = (z > 0)      ? *(const float4*)(c + zoff - PLANE) : zero;
    const float4 cp = (z < DZ - 1) ? *(const float4*)(c + zoff + PLANE) : zero;
    const float4 ym = (y > 0)      ? *(const float4*)(c + zoff - W)     : zero;
    const float4 yp = (y < H - 1)  ? *(const float4*)(c + zoff + W)     : zero;
    const float  xl = (x4 > 0)     ? c[zoff - 1] : 0.f;
    const float  xr = (x4 + 4 < W) ? c[zoff + 4] : 0.f;
    const float4 Dv = *(const float4*)(Dm  + zoff);
    const float4 rv = *(const float4*)(rho + zoff);

    const float delta_t = dt[0] / (float)steps[0];

    float4 lap;
    lap.x = xl   + cc.y + ym.x + yp.x + cm.x + cp.x - 6.0f * cc.x;
    lap.y = cc.x + cc.z + ym.y + yp.y + cm.y + cp.y - 6.0f * cc.y;
    lap.z = cc.y + cc.w + ym.z + yp.z + cm.z + cp.z - 6.0f * cc.z;
    lap.w = cc.z + xr   + ym.w + yp.w + cm.w + cp.w - 6.0f * cc.w;

    float4 v;
    v.x = cc.x + (Dv.x * lap.x + rv.x * cc.x * (1.0f - cc.x)) * delta_t;
    v.y = cc.y + (Dv.y * lap.y + rv.y * cc.y * (1.0f - cc.y)) * delta_t;
    v.z = cc.z + (Dv.z * lap.z + rv.z * cc.z * (1.0f - cc.z)) * delta_t;
    v.w = cc.w + (Dv.w * lap.w + rv.w * cc.w * (1.0f - cc.w)) * delta_t;

    v.x = fminf(fmaxf(v.x, 0.f), 1.f);
    v.y = fminf(fmaxf(v.y, 0.f), 1.f);
    v.z = fminf(fmaxf(v.z, 0.f), 1.f);
    v.w = fminf(fmaxf(v.w, 0.f), 1.f);

    *(float4*)(out + zoff) = v;
}

extern "C" void kernel_launch(void* const* d_in, const int* in_sizes, int n_in,
                              void* d_out, int out_size, void* d_ws, size_t ws_size,
                              hipStream_t stream) {
    const float* c_init = (const float*)d_in[0];
    const float* Dm     = (const float*)d_in[1];
    const float* rho    = (const float*)d_in[2];
    const float* dt     = (const float*)d_in[3];
    const int*   steps  = (const int*)d_in[4];   // value 20 (fixed by setup_inputs)

    float* bufA = (float*)d_ws;
    float* bufB = bufA + NELEM;
    float* outp = (float*)d_out;
    float* bufs[2] = { bufA, bufB };

    const int NSTEPS = 20;  // must match steps[0]; launch count is host-side

    dim3 block(XT, YB, 1);           // 192 threads = 3 waves
    dim3 grid(H / YB, DZ, 1);        // 48 x 192 = 9216 blocks

    const float* src = c_init;
    for (int s = 0; s < NSTEPS; ++s) {
        float* dst = (s == NSTEPS - 1) ? outp : bufs[s & 1];
        rd_step<<<grid, block, 0, stream>>>(src, Dm, rho, dt, steps, dst);
        src = dst;
    }
}